// Round 3
// baseline (14330.836 us; speedup 1.0000x reference)
//
#include <hip/hip_runtime.h>
#include <stdint.h>
#include <math.h>

#define B 4
#define N 100000
#define C 128
#define F 256
#define ITERS 25
#define TOPK 15
#define NEGV -1e30f
#define TPB 256
#define NBLK ((N + TPB - 1) / TPB)   // 391

// monotone float->uint (order-preserving)
__device__ __forceinline__ uint32_t f2u(float f) {
    uint32_t u = __float_as_uint(f);
    return (u & 0x80000000u) ? ~u : (u | 0x80000000u);
}
__device__ __forceinline__ float u2f(uint32_t u) {
    uint32_t bits = (u & 0x80000000u) ? (u & 0x7FFFFFFFu) : ~u;
    return __uint_as_float(bits);
}

// bit-exact emulation of numpy f32: 2.0*(p@c.T) - |p|^2 - |c|^2
// dot = fma(z,c2, fma(y,c1, rn(x*c0)))  (BLAS ascending-k FMA chain)
__device__ __forceinline__ float sim_np(float x, float y, float z, float an,
                                        float c0, float c1, float c2, float cn) {
    float dot = __fmaf_rn(z, c2, __fmaf_rn(y, c1, __fmul_rn(x, c0)));
    float t = __fmul_rn(2.0f, dot);   // exact (power of 2)
    t = __fsub_rn(t, an);
    return __fsub_rn(t, cn);
}
__device__ __forceinline__ float norm3_np(float x, float y, float z) {
    // numpy sum over 3 elems: (x*x + y*y) + z*z, each op rounded
    return __fadd_rn(__fadd_rn(__fmul_rn(x, x), __fmul_rn(y, y)), __fmul_rn(z, z));
}

__global__ void k_copyf(const float* __restrict__ src, float* __restrict__ dst, int n) {
    int i = blockIdx.x * blockDim.x + threadIdx.x;
    if (i < n) dst[i] = src[i];
}

// assignment (bit-exact f32 argmax) + per-block stable ranks + block histogram
__global__ __launch_bounds__(TPB) void k_assign(const float* __restrict__ pts,
        const float* __restrict__ cent, int* __restrict__ closest,
        unsigned char* __restrict__ rank8, unsigned int* __restrict__ blockhist) {
    __shared__ float sc[C * 3];
    __shared__ float cn[C];
    __shared__ unsigned char clid[TPB];
    __shared__ unsigned int hist[C];
    const int b = blockIdx.y;
    const int blk = blockIdx.x;
    const int tid = threadIdx.x;

    for (int i = tid; i < C * 3; i += TPB) sc[i] = cent[b * C * 3 + i];
    if (tid < C) hist[tid] = 0u;
    __syncthreads();
    if (tid < C) cn[tid] = norm3_np(sc[3 * tid], sc[3 * tid + 1], sc[3 * tid + 2]);
    __syncthreads();

    const int p = blk * TPB + tid;
    int bi = 0;
    bool valid = (p < N);
    if (valid) {
        const float* pp = pts + ((size_t)b * N + (size_t)p) * 3;
        float x = pp[0], y = pp[1], z = pp[2];
        float an = norm3_np(x, y, z);
        float best = -INFINITY;
        for (int c = 0; c < C; ++c) {
            float s = sim_np(x, y, z, an, sc[3 * c], sc[3 * c + 1], sc[3 * c + 2], cn[c]);
            if (s > best) { best = s; bi = c; }   // strict > = np.argmax first-max
        }
        closest[b * N + p] = bi;
        clid[tid] = (unsigned char)bi;
        atomicAdd(&hist[bi], 1u);
    } else {
        clid[tid] = 0xFF;
    }
    __syncthreads();
    if (valid) {
        // stable in-block rank: count same-cluster threads with smaller tid
        int r = 0;
        for (int j = 0; j < tid; ++j) r += (clid[j] == (unsigned char)bi);
        rank8[b * N + p] = (unsigned char)r;
    }
    unsigned int* dst = blockhist + ((size_t)(b * NBLK + blk)) * C;
    for (int i = tid; i < C; i += TPB) dst[i] = hist[i];
}

// exclusive scan of block histograms per (b,c) -> per-block base + total count
__global__ __launch_bounds__(64) void k_colscan(const unsigned int* __restrict__ blockhist,
        unsigned int* __restrict__ blockbase, unsigned int* __restrict__ cnt) {
    __shared__ unsigned int sh[NBLK];
    const int c = blockIdx.x;
    const int b = blockIdx.y;
    const int tid = threadIdx.x;
    for (int i = tid; i < NBLK; i += 64) sh[i] = blockhist[((size_t)(b * NBLK + i)) * C + c];
    __syncthreads();
    if (tid == 0) {
        unsigned int run = 0;
        for (int i = 0; i < NBLK; ++i) { unsigned int t = sh[i]; sh[i] = run; run += t; }
        cnt[b * C + c] = run;
    }
    __syncthreads();
    for (int i = tid; i < NBLK; i += 64) blockbase[((size_t)(b * NBLK + i)) * C + c] = sh[i];
}

// exclusive scan of cluster counts -> cluster base offsets; counts as f32
__global__ __launch_bounds__(64) void k_cbase(const unsigned int* __restrict__ cnt,
        unsigned int* __restrict__ clusterbase, float* __restrict__ cntf) {
    const int b = blockIdx.x;
    const int tid = threadIdx.x;
    if (tid == 0) {
        unsigned int run = 0;
        for (int c = 0; c < C; ++c) { clusterbase[b * C + c] = run; run += cnt[b * C + c]; }
    }
    for (int c = tid; c < C; c += 64) cntf[b * C + c] = (float)cnt[b * C + c];
}

// scatter points into member lists (ascending index order within cluster)
__global__ __launch_bounds__(TPB) void k_scatter(const int* __restrict__ closest,
        const unsigned char* __restrict__ rank8, const unsigned int* __restrict__ clusterbase,
        const unsigned int* __restrict__ blockbase, unsigned int* __restrict__ ml) {
    const int b = blockIdx.y;
    const int blk = blockIdx.x;
    const int p = blk * TPB + threadIdx.x;
    if (p < N) {
        int c = closest[b * N + p];
        unsigned int pos = clusterbase[b * C + c]
                         + blockbase[((size_t)(b * NBLK + blk)) * C + c]
                         + (unsigned int)rank8[b * N + p];
        ml[(size_t)b * N + pos] = (unsigned int)p;
    }
}

// sequential f32 per-cluster sums in index order (bit-exact segment_sum), then divide
__global__ __launch_bounds__(512) void k_segsum(const float* __restrict__ pts,
        const unsigned int* __restrict__ ml, const unsigned int* __restrict__ clusterbase,
        const unsigned int* __restrict__ cnt, const float* __restrict__ cntf,
        float* __restrict__ cent_next) {
    const int b = blockIdx.x;
    const int c = threadIdx.x >> 2;
    const int j = threadIdx.x & 3;
    if (j == 3) return;
    const unsigned int base = clusterbase[b * C + c];
    const unsigned int n = cnt[b * C + c];
    const unsigned int* list = ml + (size_t)b * N + base;
    const float* P = pts + (size_t)b * N * 3;
    float s = 0.f;
    for (unsigned int i = 0; i < n; ++i) {
        unsigned int p = list[i];
        s = __fadd_rn(s, P[p * 3 + j]);    // sequential, ascending index: np order
    }
    float denom = __fadd_rn(cntf[b * C + c], 1e-8f);
    cent_next[(b * C + c) * 3 + j] = __fdiv_rn(s, denom);
}

// final bit-exact f32 sim of each point to its assigned cluster's FINAL centroid
__global__ __launch_bounds__(TPB) void k_score(const float* __restrict__ pts,
        const float* __restrict__ cent, const int* __restrict__ closest,
        float* __restrict__ scores) {
    __shared__ float sc[C * 3];
    __shared__ float cn[C];
    const int b = blockIdx.y;
    const int tid = threadIdx.x;
    for (int i = tid; i < C * 3; i += TPB) sc[i] = cent[b * C * 3 + i];
    __syncthreads();
    if (tid < C) cn[tid] = norm3_np(sc[3 * tid], sc[3 * tid + 1], sc[3 * tid + 2]);
    __syncthreads();
    const int p = blockIdx.x * TPB + tid;
    if (p < N) {
        const float* pp = pts + ((size_t)b * N + (size_t)p) * 3;
        float x = pp[0], y = pp[1], z = pp[2];
        float an = norm3_np(x, y, z);
        int c = closest[b * N + p];
        scores[b * N + p] = sim_np(x, y, z, an, sc[3 * c], sc[3 * c + 1], sc[3 * c + 2], cn[c]);
    }
}

// per-cluster top-15 (stable: ties -> smaller index) + f32 softmax weights
__global__ __launch_bounds__(TPB) void k_topk(const int* __restrict__ closest,
        const float* __restrict__ scores, int* __restrict__ tk_idx,
        float* __restrict__ tk_w) {
    const int b = blockIdx.y;
    const int c = blockIdx.x;
    const int tid = threadIdx.x;
    const int* cl = closest + (size_t)b * N;
    const float* ss = scores + (size_t)b * N;

    unsigned long long a[TOPK];
    #pragma unroll
    for (int i = 0; i < TOPK; ++i) a[i] = 0ull;

    for (int p = tid; p < N; p += TPB) {
        if (cl[p] == c) {
            unsigned long long key = ((unsigned long long)f2u(ss[p]) << 32) | (uint32_t)(~p);
            if (key > a[0]) {
                a[0] = key;
                #pragma unroll
                for (int j = 0; j < TOPK - 1; ++j) {
                    if (a[j] > a[j + 1]) {
                        unsigned long long t = a[j]; a[j] = a[j + 1]; a[j + 1] = t;
                    }
                }
            }
        }
    }

    __shared__ unsigned long long wred[4];
    __shared__ unsigned long long sel;
    __shared__ unsigned long long res[TOPK];
    const int lane = tid & 63;
    const int wid = tid >> 6;

    for (int r = 0; r < TOPK; ++r) {
        unsigned long long m = a[TOPK - 1];
        #pragma unroll
        for (int off = 32; off >= 1; off >>= 1) {
            unsigned long long o = __shfl_xor(m, off, 64);
            if (o > m) m = o;
        }
        if (lane == 0) wred[wid] = m;
        __syncthreads();
        if (tid == 0) {
            unsigned long long g = wred[0];
            #pragma unroll
            for (int w = 1; w < 4; ++w) if (wred[w] > g) g = wred[w];
            sel = g;
            res[r] = g;
        }
        __syncthreads();
        if (sel != 0ull && a[TOPK - 1] == sel) {
            #pragma unroll
            for (int j = TOPK - 1; j > 0; --j) a[j] = a[j - 1];
            a[0] = 0ull;
        }
    }

    if (tid == 0) {
        float s_[TOPK]; int id_[TOPK];
        for (int i = 0; i < TOPK; ++i) {
            unsigned long long g = res[i];
            if (g == 0ull) { s_[i] = NEGV; id_[i] = 0; }
            else { s_[i] = u2f((uint32_t)(g >> 32)); id_[i] = (int)(~(uint32_t)g); }
        }
        float smax = (s_[0] > 0.5f * NEGV) ? s_[0] : NEGV;
        float w[TOPK]; float sum = 0.f;
        for (int i = 0; i < TOPK; ++i) {
            bool valid = s_[i] > 0.5f * NEGV;
            w[i] = valid ? expf(__fsub_rn(s_[i], smax)) : 0.f;
            sum = __fadd_rn(sum, w[i]);
        }
        float den = fmaxf(sum, 1e-30f);
        for (int i = 0; i < TOPK; ++i) {
            tk_idx[((size_t)b * C + c) * TOPK + i] = id_[i];
            tk_w [((size_t)b * C + c) * TOPK + i] = __fdiv_rn(w[i], den);
        }
    }
}

// cluster_features[b][f][c] = sum_k w * ft[b][f][idx]
__global__ __launch_bounds__(128) void k_feat(const float* __restrict__ ft,
        const int* __restrict__ tk_idx, const float* __restrict__ tk_w,
        float* __restrict__ out_cf) {
    const int b = blockIdx.y;
    const int f = blockIdx.x;
    const int c = threadIdx.x;
    __shared__ int sid[C * TOPK];
    __shared__ float sw[C * TOPK];
    for (int i = c; i < C * TOPK; i += 128) {
        sid[i] = tk_idx[(size_t)b * C * TOPK + i];
        sw[i]  = tk_w [(size_t)b * C * TOPK + i];
    }
    __syncthreads();
    const float* row = ft + (size_t)b * F * N + (size_t)f * N;
    float acc = 0.f;
    #pragma unroll
    for (int k = 0; k < TOPK; ++k) {
        acc = __fmaf_rn(sw[c * TOPK + k], row[sid[c * TOPK + k]], acc);
    }
    out_cf[((size_t)b * F + f) * C + c] = acc;
}

extern "C" void kernel_launch(void* const* d_in, const int* in_sizes, int n_in,
                              void* d_out, int out_size, void* d_ws, size_t ws_size,
                              hipStream_t stream) {
    (void)in_sizes; (void)n_in; (void)out_size; (void)ws_size;
    const float* pts = (const float*)d_in[0];   // (B,N,3)
    const float* ft  = (const float*)d_in[1];   // (B,F,N)
    const float* ct0 = (const float*)d_in[2];   // (B,C,3)
    float* out = (float*)d_out;                 // [B*C*3 | B*F*C]

    float* ws = (float*)d_ws;
    float* centA = ws;                                   // B*C*3
    float* centB = centA + B * C * 3;                    // B*C*3
    float* scores = centB + B * C * 3;                   // B*N
    float* cntf = scores + (size_t)B * N;                // B*C
    float* tk_w = cntf + B * C;                          // B*C*TOPK
    int* tk_idx = (int*)(tk_w + B * C * TOPK);           // B*C*TOPK
    int* closest = tk_idx + B * C * TOPK;                // B*N
    unsigned int* cnt = (unsigned int*)(closest + (size_t)B * N);       // B*C
    unsigned int* clusterbase = cnt + B * C;                            // B*C
    unsigned int* ml = clusterbase + B * C;                             // B*N
    unsigned int* blockhist = ml + (size_t)B * N;                       // B*NBLK*C
    unsigned int* blockbase = blockhist + (size_t)B * NBLK * C;         // B*NBLK*C
    unsigned char* rank8 = (unsigned char*)(blockbase + (size_t)B * NBLK * C);  // B*N bytes

    k_copyf<<<dim3((B * C * 3 + 255) / 256), dim3(256), 0, stream>>>(ct0, centA, B * C * 3);

    float* cur = centA;
    float* nxt = centB;
    for (int t = 0; t < ITERS; ++t) {
        k_assign <<<dim3(NBLK, B), dim3(TPB), 0, stream>>>(pts, cur, closest, rank8, blockhist);
        k_colscan<<<dim3(C, B),    dim3(64),  0, stream>>>(blockhist, blockbase, cnt);
        k_cbase  <<<dim3(B),       dim3(64),  0, stream>>>(cnt, clusterbase, cntf);
        k_scatter<<<dim3(NBLK, B), dim3(TPB), 0, stream>>>(closest, rank8, clusterbase, blockbase, ml);
        k_segsum <<<dim3(B),       dim3(512), 0, stream>>>(pts, ml, clusterbase, cnt, cntf, nxt);
        float* tmp = cur; cur = nxt; nxt = tmp;
    }
    k_score<<<dim3(NBLK, B), dim3(TPB), 0, stream>>>(pts, cur, closest, scores);
    k_topk <<<dim3(C, B),    dim3(TPB), 0, stream>>>(closest, scores, tk_idx, tk_w);
    k_feat <<<dim3(F, B),    dim3(128), 0, stream>>>(ft, tk_idx, tk_w, out + B * C * 3);
    k_copyf<<<dim3((B * C * 3 + 255) / 256), dim3(256), 0, stream>>>(cur, out, B * C * 3);
}

// Round 4
// 4351.865 us; speedup vs baseline: 3.2930x; 3.2930x over previous
//
#include <hip/hip_runtime.h>
#include <stdint.h>
#include <math.h>

#define B 4
#define N 100000
#define C 128
#define F 256
#define ITERS 25
#define TOPK 15
#define NEGV -1e30f
#define TPB 256
#define NBLK ((N + TPB - 1) / TPB)   // 391

// monotone float->uint (order-preserving)
__device__ __forceinline__ uint32_t f2u(float f) {
    uint32_t u = __float_as_uint(f);
    return (u & 0x80000000u) ? ~u : (u | 0x80000000u);
}
__device__ __forceinline__ float u2f(uint32_t u) {
    uint32_t bits = (u & 0x80000000u) ? (u & 0x7FFFFFFFu) : ~u;
    return __uint_as_float(bits);
}

// bit-exact emulation of numpy f32: 2.0*(p@c.T) - |p|^2 - |c|^2
__device__ __forceinline__ float sim_np(float x, float y, float z, float an,
                                        float c0, float c1, float c2, float cn) {
    float dot = __fmaf_rn(z, c2, __fmaf_rn(y, c1, __fmul_rn(x, c0)));
    float t = __fmul_rn(2.0f, dot);   // exact
    t = __fsub_rn(t, an);
    return __fsub_rn(t, cn);
}
__device__ __forceinline__ float norm3_np(float x, float y, float z) {
    return __fadd_rn(__fadd_rn(__fmul_rn(x, x), __fmul_rn(y, y)), __fmul_rn(z, z));
}

__global__ void k_copyf(const float* __restrict__ src, float* __restrict__ dst, int n) {
    int i = blockIdx.x * blockDim.x + threadIdx.x;
    if (i < n) dst[i] = src[i];
}

// assignment (bit-exact f32 argmax) + per-block stable ranks + block histogram
__global__ __launch_bounds__(TPB) void k_assign(const float* __restrict__ pts,
        const float* __restrict__ cent, int* __restrict__ closest,
        unsigned char* __restrict__ rank8, unsigned int* __restrict__ blockhist) {
    __shared__ float sc[C * 3];
    __shared__ float cn[C];
    __shared__ unsigned char clid[TPB];
    __shared__ unsigned int hist[C];
    const int b = blockIdx.y;
    const int blk = blockIdx.x;
    const int tid = threadIdx.x;

    for (int i = tid; i < C * 3; i += TPB) sc[i] = cent[b * C * 3 + i];
    if (tid < C) hist[tid] = 0u;
    __syncthreads();
    if (tid < C) cn[tid] = norm3_np(sc[3 * tid], sc[3 * tid + 1], sc[3 * tid + 2]);
    __syncthreads();

    const int p = blk * TPB + tid;
    int bi = 0;
    bool valid = (p < N);
    if (valid) {
        const float* pp = pts + ((size_t)b * N + (size_t)p) * 3;
        float x = pp[0], y = pp[1], z = pp[2];
        float an = norm3_np(x, y, z);
        float best = -INFINITY;
        #pragma unroll 8
        for (int c = 0; c < C; ++c) {
            float s = sim_np(x, y, z, an, sc[3 * c], sc[3 * c + 1], sc[3 * c + 2], cn[c]);
            if (s > best) { best = s; bi = c; }   // strict > = np.argmax first-max
        }
        closest[b * N + p] = bi;
        clid[tid] = (unsigned char)bi;
        atomicAdd(&hist[bi], 1u);
    } else {
        clid[tid] = 0xFF;
    }
    __syncthreads();
    if (valid) {
        int r = 0;
        #pragma unroll 8
        for (int j = 0; j < tid; ++j) r += (clid[j] == (unsigned char)bi);
        rank8[b * N + p] = (unsigned char)r;
    }
    unsigned int* dst = blockhist + ((size_t)(b * NBLK + blk)) * C;
    for (int i = tid; i < C; i += TPB) dst[i] = hist[i];
}

// fused: in-place exclusive scan of block histograms (per cluster) + cluster bases
__global__ __launch_bounds__(128) void k_scan(unsigned int* __restrict__ blockhist,
        unsigned int* __restrict__ cnt, unsigned int* __restrict__ clusterbase) {
    __shared__ unsigned int stot[C];
    __shared__ unsigned int sbase[C];
    const int b = blockIdx.x;
    const int c = threadIdx.x;   // 128
    unsigned int run = 0;
    #pragma unroll 4
    for (int i = 0; i < NBLK; ++i) {
        size_t off = ((size_t)(b * NBLK + i)) * C + c;
        unsigned int v = blockhist[off];
        blockhist[off] = run;     // becomes per-block base
        run += v;
    }
    cnt[b * C + c] = run;
    stot[c] = run;
    __syncthreads();
    if (c == 0) {
        unsigned int acc = 0;
        for (int k = 0; k < C; ++k) { sbase[k] = acc; acc += stot[k]; }
    }
    __syncthreads();
    clusterbase[b * C + c] = sbase[c];
}

// scatter points into member lists (ascending index order within cluster)
__global__ __launch_bounds__(TPB) void k_scatter(const int* __restrict__ closest,
        const unsigned char* __restrict__ rank8, const unsigned int* __restrict__ clusterbase,
        const unsigned int* __restrict__ blockbase, unsigned int* __restrict__ ml) {
    const int b = blockIdx.y;
    const int blk = blockIdx.x;
    const int p = blk * TPB + threadIdx.x;
    if (p < N) {
        int c = closest[b * N + p];
        unsigned int pos = clusterbase[b * C + c]
                         + blockbase[((size_t)(b * NBLK + blk)) * C + c]
                         + (unsigned int)rank8[b * N + p];
        ml[(size_t)b * N + pos] = (unsigned int)p;
    }
}

// sequential f32 per-cluster sums in index order (bit-exact), batch-prefetched.
// one thread per (b,c,j) chain; 24 blocks x 64.
__global__ __launch_bounds__(64) void k_segsum(const float* __restrict__ pts,
        const unsigned int* __restrict__ ml, const unsigned int* __restrict__ clusterbase,
        const unsigned int* __restrict__ cnt, float* __restrict__ cent_next) {
    const int id = blockIdx.x * 64 + threadIdx.x;   // 0..1535
    const int b = id / (C * 3);
    const int rem = id % (C * 3);
    const int c = rem / 3;
    const int j = rem % 3;
    const unsigned int base = clusterbase[b * C + c];
    const unsigned int n = cnt[b * C + c];
    const unsigned int* list = ml + (size_t)b * N + base;
    const float* P = pts + (size_t)b * N * 3;
    float s = 0.f;
    unsigned int i = 0;
    for (; i + 32 <= n; i += 32) {
        unsigned int pidx[32];
        #pragma unroll
        for (int u = 0; u < 32; ++u) pidx[u] = list[i + u];
        float t[32];
        #pragma unroll
        for (int u = 0; u < 32; ++u) t[u] = P[pidx[u] * 3 + j];
        #pragma unroll
        for (int u = 0; u < 32; ++u) s = __fadd_rn(s, t[u]);   // strict np order
    }
    for (; i < n; ++i) s = __fadd_rn(s, P[list[i] * 3 + j]);
    float denom = __fadd_rn((float)n, 1e-8f);
    cent_next[(b * C + c) * 3 + j] = __fdiv_rn(s, denom);
}

// per-cluster top-15 over MEMBERS ONLY (sims computed inline vs final centroids),
// stable tie-break (smaller index), f32 softmax weights
__global__ __launch_bounds__(TPB) void k_topk(const unsigned int* __restrict__ ml,
        const unsigned int* __restrict__ clusterbase, const unsigned int* __restrict__ cnt,
        const float* __restrict__ pts, const float* __restrict__ cent,
        int* __restrict__ tk_idx, float* __restrict__ tk_w) {
    const int b = blockIdx.y;
    const int c = blockIdx.x;
    const int tid = threadIdx.x;
    const unsigned int base = clusterbase[b * C + c];
    const unsigned int n = cnt[b * C + c];
    const unsigned int* list = ml + (size_t)b * N + base;
    const float* P = pts + (size_t)b * N * 3;

    const float c0 = cent[(b * C + c) * 3 + 0];
    const float c1 = cent[(b * C + c) * 3 + 1];
    const float c2 = cent[(b * C + c) * 3 + 2];
    const float cnorm = norm3_np(c0, c1, c2);

    unsigned long long a[TOPK];
    #pragma unroll
    for (int i = 0; i < TOPK; ++i) a[i] = 0ull;

    for (unsigned int i = tid; i < n; i += TPB) {
        unsigned int p = list[i];
        float x = P[p * 3 + 0], y = P[p * 3 + 1], z = P[p * 3 + 2];
        float an = norm3_np(x, y, z);
        float s = sim_np(x, y, z, an, c0, c1, c2, cnorm);
        unsigned long long key = ((unsigned long long)f2u(s) << 32) | (uint32_t)(~p);
        if (key > a[0]) {
            a[0] = key;
            #pragma unroll
            for (int j = 0; j < TOPK - 1; ++j) {
                if (a[j] > a[j + 1]) {
                    unsigned long long t = a[j]; a[j] = a[j + 1]; a[j + 1] = t;
                }
            }
        }
    }

    __shared__ unsigned long long wred[4];
    __shared__ unsigned long long sel;
    __shared__ unsigned long long res[TOPK];
    const int lane = tid & 63;
    const int wid = tid >> 6;

    for (int r = 0; r < TOPK; ++r) {
        unsigned long long m = a[TOPK - 1];
        #pragma unroll
        for (int off = 32; off >= 1; off >>= 1) {
            unsigned long long o = __shfl_xor(m, off, 64);
            if (o > m) m = o;
        }
        if (lane == 0) wred[wid] = m;
        __syncthreads();
        if (tid == 0) {
            unsigned long long g = wred[0];
            #pragma unroll
            for (int w = 1; w < 4; ++w) if (wred[w] > g) g = wred[w];
            sel = g;
            res[r] = g;
        }
        __syncthreads();
        if (sel != 0ull && a[TOPK - 1] == sel) {
            #pragma unroll
            for (int j = TOPK - 1; j > 0; --j) a[j] = a[j - 1];
            a[0] = 0ull;
        }
    }

    if (tid == 0) {
        float s_[TOPK]; int id_[TOPK];
        for (int i = 0; i < TOPK; ++i) {
            unsigned long long g = res[i];
            if (g == 0ull) { s_[i] = NEGV; id_[i] = 0; }
            else { s_[i] = u2f((uint32_t)(g >> 32)); id_[i] = (int)(~(uint32_t)g); }
        }
        float smax = (s_[0] > 0.5f * NEGV) ? s_[0] : NEGV;
        float w[TOPK]; float sum = 0.f;
        for (int i = 0; i < TOPK; ++i) {
            bool valid = s_[i] > 0.5f * NEGV;
            w[i] = valid ? expf(__fsub_rn(s_[i], smax)) : 0.f;
            sum = __fadd_rn(sum, w[i]);
        }
        float den = fmaxf(sum, 1e-30f);
        for (int i = 0; i < TOPK; ++i) {
            tk_idx[((size_t)b * C + c) * TOPK + i] = id_[i];
            tk_w [((size_t)b * C + c) * TOPK + i] = __fdiv_rn(w[i], den);
        }
    }
}

// cluster_features[b][f][c] = sum_k w * ft[b][f][idx]
__global__ __launch_bounds__(128) void k_feat(const float* __restrict__ ft,
        const int* __restrict__ tk_idx, const float* __restrict__ tk_w,
        float* __restrict__ out_cf) {
    const int b = blockIdx.y;
    const int f = blockIdx.x;
    const int c = threadIdx.x;
    __shared__ int sid[C * TOPK];
    __shared__ float sw[C * TOPK];
    for (int i = c; i < C * TOPK; i += 128) {
        sid[i] = tk_idx[(size_t)b * C * TOPK + i];
        sw[i]  = tk_w [(size_t)b * C * TOPK + i];
    }
    __syncthreads();
    const float* row = ft + (size_t)b * F * N + (size_t)f * N;
    float acc = 0.f;
    #pragma unroll
    for (int k = 0; k < TOPK; ++k) {
        acc = __fmaf_rn(sw[c * TOPK + k], row[sid[c * TOPK + k]], acc);
    }
    out_cf[((size_t)b * F + f) * C + c] = acc;
}

extern "C" void kernel_launch(void* const* d_in, const int* in_sizes, int n_in,
                              void* d_out, int out_size, void* d_ws, size_t ws_size,
                              hipStream_t stream) {
    (void)in_sizes; (void)n_in; (void)out_size; (void)ws_size;
    const float* pts = (const float*)d_in[0];   // (B,N,3)
    const float* ft  = (const float*)d_in[1];   // (B,F,N)
    const float* ct0 = (const float*)d_in[2];   // (B,C,3)
    float* out = (float*)d_out;                 // [B*C*3 | B*F*C]

    float* ws = (float*)d_ws;
    float* centA = ws;                                   // B*C*3
    float* centB = centA + B * C * 3;                    // B*C*3
    float* tk_w = centB + B * C * 3;                     // B*C*TOPK
    int* tk_idx = (int*)(tk_w + B * C * TOPK);           // B*C*TOPK
    int* closest = tk_idx + B * C * TOPK;                // B*N
    unsigned int* cnt = (unsigned int*)(closest + (size_t)B * N);   // B*C
    unsigned int* clusterbase = cnt + B * C;                        // B*C
    unsigned int* ml = clusterbase + B * C;                         // B*N
    unsigned int* blockhist = ml + (size_t)B * N;                   // B*NBLK*C (scan in-place)
    unsigned char* rank8 = (unsigned char*)(blockhist + (size_t)B * NBLK * C);  // B*N bytes

    const float* cur = ct0;          // t=0 reads initial centroids directly
    float* nxt = centA;
    for (int t = 0; t < ITERS; ++t) {
        k_assign <<<dim3(NBLK, B), dim3(TPB), 0, stream>>>(pts, cur, closest, rank8, blockhist);
        k_scan   <<<dim3(B),       dim3(128), 0, stream>>>(blockhist, cnt, clusterbase);
        k_scatter<<<dim3(NBLK, B), dim3(TPB), 0, stream>>>(closest, rank8, clusterbase, blockhist, ml);
        k_segsum <<<dim3(24),      dim3(64),  0, stream>>>(pts, ml, clusterbase, cnt, nxt);
        cur = nxt;
        nxt = (nxt == centA) ? centB : centA;
    }
    // cur = final centroids; ml/cnt/clusterbase = partition by final closest
    k_topk<<<dim3(C, B), dim3(TPB), 0, stream>>>(ml, clusterbase, cnt, pts, cur, tk_idx, tk_w);
    k_feat<<<dim3(F, B), dim3(128), 0, stream>>>(ft, tk_idx, tk_w, out + B * C * 3);
    k_copyf<<<dim3((B * C * 3 + 255) / 256), dim3(256), 0, stream>>>(cur, out, B * C * 3);
}